// Round 2
// baseline (1300.722 us; speedup 1.0000x reference)
//
#include <hip/hip_runtime.h>

#define D 128

// ---------------------------------------------------------------------------
// Kernel 1: Ah = h@WA + bA, Bh = h@WB + bB   (fp32 GEMV-batch, 8 rows/wave)
// ---------------------------------------------------------------------------
__launch_bounds__(256, 2)
__global__ void gemm_ab(const float* __restrict__ h,
                        const float* __restrict__ WA, const float* __restrict__ bA,
                        const float* __restrict__ WB, const float* __restrict__ bB,
                        float* __restrict__ Ah, float* __restrict__ Bh, int N)
{
    __shared__ float hs[32][128];           // 16 KB: 32 rows of h
    const int tid = threadIdx.x;
    const int r0  = blockIdx.x * 32;

    // stage 32 rows, float4-coalesced
    #pragma unroll
    for (int j = 0; j < 4; ++j) {
        int idx4 = tid + j * 256;           // 0..1023 float4 slots
        int row  = idx4 >> 5;               // 32 float4 per row
        int c4   = (idx4 & 31) * 4;
        int gr   = r0 + row;
        float4 v = make_float4(0.f, 0.f, 0.f, 0.f);
        if (gr < N) v = *(const float4*)&h[(size_t)gr * D + c4];
        *(float4*)&hs[row][c4] = v;
    }
    __syncthreads();

    const int wave = tid >> 6, lane = tid & 63;
    const int lr    = wave * 8;
    const int rbase = r0 + lr;
    if (rbase >= N) return;

    float a0[8], a1[8], b0[8], b1[8];
    #pragma unroll
    for (int r = 0; r < 8; ++r) { a0[r] = a1[r] = b0[r] = b1[r] = 0.f; }

    for (int k4 = 0; k4 < 32; ++k4) {
        float4 hv[8];
        #pragma unroll
        for (int r = 0; r < 8; ++r)
            hv[r] = *(const float4*)&hs[lr + r][k4 * 4];   // LDS broadcast reads
        #pragma unroll
        for (int kk = 0; kk < 4; ++kk) {
            const int k = k4 * 4 + kk;
            const float wa0 = WA[k * D + lane], wa1 = WA[k * D + 64 + lane];
            const float wb0 = WB[k * D + lane], wb1 = WB[k * D + 64 + lane];
            #pragma unroll
            for (int r = 0; r < 8; ++r) {
                const float hk = ((const float*)&hv[r])[kk];
                a0[r] = fmaf(hk, wa0, a0[r]);
                a1[r] = fmaf(hk, wa1, a1[r]);
                b0[r] = fmaf(hk, wb0, b0[r]);
                b1[r] = fmaf(hk, wb1, b1[r]);
            }
        }
    }

    const float biasA0 = bA[lane], biasA1 = bA[64 + lane];
    const float biasB0 = bB[lane], biasB1 = bB[64 + lane];
    #pragma unroll
    for (int r = 0; r < 8; ++r) {
        const int gr = rbase + r;
        if (gr < N) {
            Ah[(size_t)gr * D + lane]      = a0[r] + biasA0;
            Ah[(size_t)gr * D + 64 + lane] = a1[r] + biasA1;
            Bh[(size_t)gr * D + lane]      = b0[r] + biasB0;
            Bh[(size_t)gr * D + 64 + lane] = b1[r] + biasB1;
        }
    }
}

// ---------------------------------------------------------------------------
// Kernel 2: per-edge gated message + segment-max via uint atomicMax.
// msg >= 0, so nonneg-float bit pattern order == float order; c init'd to 0
// implements the max(c, 0) clamp for zero-in-degree nodes.
// ---------------------------------------------------------------------------
__launch_bounds__(256)
__global__ void edge_kernel(const float* __restrict__ Ah,
                            const float* __restrict__ Bh,
                            const int* __restrict__ src,
                            const int* __restrict__ dst,
                            unsigned* __restrict__ c_bits, int E)
{
    const int t = blockIdx.x * 256 + threadIdx.x;
    const int e = t >> 5;                  // 32 threads per edge, 4 feats each
    if (e >= E) return;
    const int sub = t & 31;
    const int s = src[e], d = dst[e];

    const float4 bs = *(const float4*)&Bh[(size_t)s * D + sub * 4];
    const float4 bd = *(const float4*)&Bh[(size_t)d * D + sub * 4];
    const float4 as = *(const float4*)&Ah[(size_t)s * D + sub * 4];
    unsigned* cb = &c_bits[(size_t)d * D + sub * 4];

    #pragma unroll
    for (int j = 0; j < 4; ++j) {
        const float ev = ((const float*)&bs)[j] + ((const float*)&bd)[j];
        const float sg = 1.0f / (1.0f + __expf(-ev));
        const float pr = sg * ((const float*)&as)[j];
        const float m  = pr > 0.0f ? pr : 0.0f;   // strict: never -0.0
        atomicMax(cb + j, __float_as_uint(m));
    }
}

// ---------------------------------------------------------------------------
// Kernel 3: bundle = [h|c]@Wn + bn; L2-normalize rows; relu; residual add.
// ---------------------------------------------------------------------------
__launch_bounds__(256, 2)
__global__ void node_apply(const float* __restrict__ h,
                           const float* __restrict__ c,
                           const float* __restrict__ Wn,
                           const float* __restrict__ bn,
                           float* __restrict__ out, int N)
{
    __shared__ float hs[32][256];           // 32 KB: [h | c] per row
    const int tid = threadIdx.x;
    const int r0  = blockIdx.x * 32;

    #pragma unroll
    for (int j = 0; j < 4; ++j) {
        int idx4 = tid + j * 256;
        int row  = idx4 >> 5;
        int c4   = (idx4 & 31) * 4;
        int gr   = r0 + row;
        float4 hv = make_float4(0.f, 0.f, 0.f, 0.f);
        float4 cv = make_float4(0.f, 0.f, 0.f, 0.f);
        if (gr < N) {
            hv = *(const float4*)&h[(size_t)gr * D + c4];
            cv = *(const float4*)&c[(size_t)gr * D + c4];
        }
        *(float4*)&hs[row][c4]       = hv;
        *(float4*)&hs[row][128 + c4] = cv;
    }
    __syncthreads();

    const int wave = tid >> 6, lane = tid & 63;
    const int lr    = wave * 8;
    const int rbase = r0 + lr;
    if (rbase >= N) return;

    float a0[8], a1[8];
    #pragma unroll
    for (int r = 0; r < 8; ++r) { a0[r] = a1[r] = 0.f; }

    for (int k4 = 0; k4 < 64; ++k4) {       // K = 256
        float4 hv[8];
        #pragma unroll
        for (int r = 0; r < 8; ++r)
            hv[r] = *(const float4*)&hs[lr + r][k4 * 4];
        #pragma unroll
        for (int kk = 0; kk < 4; ++kk) {
            const int k = k4 * 4 + kk;
            const float w0 = Wn[k * D + lane], w1 = Wn[k * D + 64 + lane];
            #pragma unroll
            for (int r = 0; r < 8; ++r) {
                const float hk = ((const float*)&hv[r])[kk];
                a0[r] = fmaf(hk, w0, a0[r]);
                a1[r] = fmaf(hk, w1, a1[r]);
            }
        }
    }

    const float bn0 = bn[lane], bn1 = bn[64 + lane];
    #pragma unroll
    for (int r = 0; r < 8; ++r) {
        const int gr = rbase + r;
        float v0 = a0[r] + bn0;
        float v1 = a1[r] + bn1;
        float ss = v0 * v0 + v1 * v1;
        #pragma unroll
        for (int off = 32; off >= 1; off >>= 1)
            ss += __shfl_xor(ss, off);      // 64-lane reduce
        const float inv = 1.0f / fmaxf(sqrtf(ss), 1e-12f);
        const float o0 = hs[lr + r][lane]      + fmaxf(v0 * inv, 0.0f);
        const float o1 = hs[lr + r][64 + lane] + fmaxf(v1 * inv, 0.0f);
        if (gr < N) {
            out[(size_t)gr * D + lane]      = o0;
            out[(size_t)gr * D + 64 + lane] = o1;
        }
    }
}

// ---------------------------------------------------------------------------
extern "C" void kernel_launch(void* const* d_in, const int* in_sizes, int n_in,
                              void* d_out, int out_size, void* d_ws, size_t ws_size,
                              hipStream_t stream)
{
    const float* h   = (const float*)d_in[0];
    const int*   src = (const int*)  d_in[1];
    const int*   dst = (const int*)  d_in[2];
    const float* WA  = (const float*)d_in[3];
    const float* bA  = (const float*)d_in[4];
    const float* WB  = (const float*)d_in[5];
    const float* bB  = (const float*)d_in[6];
    const float* Wn  = (const float*)d_in[7];
    const float* bn  = (const float*)d_in[8];

    const int N = in_sizes[0] / D;
    const int E = in_sizes[1];

    float* Ah = (float*)d_ws;
    float* Bh = Ah + (size_t)N * D;
    // c lives in ws if it fits, else reuse d_out (node_apply stages c into LDS
    // per-block before overwriting its own rows, so aliasing is safe).
    const size_t need3 = (size_t)N * D * sizeof(float) * 3;
    float* c = (ws_size >= need3) ? (Bh + (size_t)N * D) : (float*)d_out;

    hipMemsetAsync(c, 0, (size_t)N * D * sizeof(float), stream);

    const int nb = (N + 31) / 32;
    gemm_ab<<<nb, 256, 0, stream>>>(h, WA, bA, WB, bB, Ah, Bh, N);

    const int eb = (int)(((long long)E * 32 + 255) / 256);
    edge_kernel<<<eb, 256, 0, stream>>>(Ah, Bh, src, dst, (unsigned*)c, E);

    node_apply<<<nb, 256, 0, stream>>>(h, c, Wn, bn, (float*)d_out, N);
}

// Round 6
// 550.278 us; speedup vs baseline: 2.3638x; 2.3638x over previous
//
#include <hip/hip_runtime.h>

#define D 128

// ---------------------------------------------------------------------------
// Kernel 1: Ah = h@WA + bA, Bh = h@WB + bB   (fp32 GEMV-batch, 8 rows/wave)
// ---------------------------------------------------------------------------
__launch_bounds__(256, 2)
__global__ void gemm_ab(const float* __restrict__ h,
                        const float* __restrict__ WA, const float* __restrict__ bA,
                        const float* __restrict__ WB, const float* __restrict__ bB,
                        float* __restrict__ Ah, float* __restrict__ Bh, int N)
{
    __shared__ float hs[32][128];           // 16 KB: 32 rows of h
    const int tid = threadIdx.x;
    const int r0  = blockIdx.x * 32;

    #pragma unroll
    for (int j = 0; j < 4; ++j) {
        int idx4 = tid + j * 256;           // 0..1023 float4 slots
        int row  = idx4 >> 5;               // 32 float4 per row
        int c4   = (idx4 & 31) * 4;
        int gr   = r0 + row;
        float4 v = make_float4(0.f, 0.f, 0.f, 0.f);
        if (gr < N) v = *(const float4*)&h[(size_t)gr * D + c4];
        *(float4*)&hs[row][c4] = v;
    }
    __syncthreads();

    const int wave = tid >> 6, lane = tid & 63;
    const int lr    = wave * 8;
    const int rbase = r0 + lr;
    if (rbase >= N) return;

    float a0[8], a1[8], b0[8], b1[8];
    #pragma unroll
    for (int r = 0; r < 8; ++r) { a0[r] = a1[r] = b0[r] = b1[r] = 0.f; }

    for (int k4 = 0; k4 < 32; ++k4) {
        float4 hv[8];
        #pragma unroll
        for (int r = 0; r < 8; ++r)
            hv[r] = *(const float4*)&hs[lr + r][k4 * 4];
        #pragma unroll
        for (int kk = 0; kk < 4; ++kk) {
            const int k = k4 * 4 + kk;
            const float wa0 = WA[k * D + lane], wa1 = WA[k * D + 64 + lane];
            const float wb0 = WB[k * D + lane], wb1 = WB[k * D + 64 + lane];
            #pragma unroll
            for (int r = 0; r < 8; ++r) {
                const float hk = ((const float*)&hv[r])[kk];
                a0[r] = fmaf(hk, wa0, a0[r]);
                a1[r] = fmaf(hk, wa1, a1[r]);
                b0[r] = fmaf(hk, wb0, b0[r]);
                b1[r] = fmaf(hk, wb1, b1[r]);
            }
        }
    }

    const float biasA0 = bA[lane], biasA1 = bA[64 + lane];
    const float biasB0 = bB[lane], biasB1 = bB[64 + lane];
    #pragma unroll
    for (int r = 0; r < 8; ++r) {
        const int gr = rbase + r;
        if (gr < N) {
            Ah[(size_t)gr * D + lane]      = a0[r] + biasA0;
            Ah[(size_t)gr * D + 64 + lane] = a1[r] + biasA1;
            Bh[(size_t)gr * D + lane]      = b0[r] + biasB0;
            Bh[(size_t)gr * D + 64 + lane] = b1[r] + biasB1;
        }
    }
}

// ---------------------------------------------------------------------------
// CSR build: histogram -> exclusive scan -> scatter (src ids grouped by dst)
// ---------------------------------------------------------------------------
__launch_bounds__(256)
__global__ void hist_kernel(const int* __restrict__ dst,
                            int* __restrict__ counters, int E)
{
    const int e = blockIdx.x * 256 + threadIdx.x;
    if (e < E) atomicAdd(&counters[dst[e]], 1);
}

__launch_bounds__(1024)
__global__ void scan_kernel(const int* __restrict__ counters,
                            int* __restrict__ row_ptr,
                            int* __restrict__ cursor, int N, int E)
{
    __shared__ int part[1024];
    const int t = threadIdx.x;
    const int chunk = (N + 1023) / 1024;
    const int base = t * chunk;

    int sum = 0;
    for (int i = 0; i < chunk; ++i) {
        int idx = base + i;
        if (idx < N) sum += counters[idx];
    }
    part[t] = sum;
    __syncthreads();

    for (int off = 1; off < 1024; off <<= 1) {   // Hillis-Steele inclusive
        int v = (t >= off) ? part[t - off] : 0;
        __syncthreads();
        part[t] += v;
        __syncthreads();
    }

    int prefix = (t == 0) ? 0 : part[t - 1];
    for (int i = 0; i < chunk; ++i) {
        int idx = base + i;
        if (idx < N) {
            row_ptr[idx] = prefix;
            cursor[idx]  = prefix;
            prefix += counters[idx];
        }
    }
    if (t == 1023) row_ptr[N] = E;
}

__launch_bounds__(256)
__global__ void scatter_kernel(const int* __restrict__ src,
                               const int* __restrict__ dst,
                               int* __restrict__ cursor,
                               int* __restrict__ edge_src, int E)
{
    const int e = blockIdx.x * 256 + threadIdx.x;
    if (e < E) {
        const int pos = atomicAdd(&cursor[dst[e]], 1);
        edge_src[pos] = src[e];
    }
}

// ---------------------------------------------------------------------------
// Kernel 2': per-dst-node gather + gated-message max-reduce, atomic-free.
// One wave per dst node; lane owns 2 features (float2). m init 0 implements
// both relu(msg) (msg<=0 never wins) and the zero-in-degree clamp.
// ---------------------------------------------------------------------------
__launch_bounds__(256)
__global__ void node_gather(const float* __restrict__ Ah,
                            const float* __restrict__ Bh,
                            const int* __restrict__ row_ptr,
                            const int* __restrict__ edge_src,
                            float* __restrict__ c, int N)
{
    const int wave = threadIdx.x >> 6, lane = threadIdx.x & 63;
    const int d = blockIdx.x * 4 + wave;
    if (d >= N) return;

    const int beg = row_ptr[d], end = row_ptr[d + 1];
    const float2 bd = *(const float2*)&Bh[(size_t)d * D + lane * 2];
    float m0 = 0.f, m1 = 0.f;

    for (int base = beg; base < end; base += 64) {
        const int cnt = min(64, end - base);
        const int sv = (lane < cnt) ? edge_src[base + lane] : 0;
        for (int i = 0; i < cnt; ++i) {
            const int s = __shfl(sv, i);
            const float2 bs = *(const float2*)&Bh[(size_t)s * D + lane * 2];
            const float2 as = *(const float2*)&Ah[(size_t)s * D + lane * 2];
            const float e0 = bs.x + bd.x, e1 = bs.y + bd.y;
            const float p0 = as.x / (1.f + __expf(-e0));
            const float p1 = as.y / (1.f + __expf(-e1));
            m0 = fmaxf(m0, p0);
            m1 = fmaxf(m1, p1);
        }
    }
    float2 o; o.x = m0; o.y = m1;
    *(float2*)&c[(size_t)d * D + lane * 2] = o;
}

// ---------------------------------------------------------------------------
// Kernel 3: bundle = [h|c]@Wn + bn; L2-normalize rows; relu; residual add.
// ---------------------------------------------------------------------------
__launch_bounds__(256, 2)
__global__ void node_apply(const float* __restrict__ h,
                           const float* __restrict__ c,
                           const float* __restrict__ Wn,
                           const float* __restrict__ bn,
                           float* __restrict__ out, int N)
{
    __shared__ float hs[32][256];           // 32 KB: [h | c] per row
    const int tid = threadIdx.x;
    const int r0  = blockIdx.x * 32;

    #pragma unroll
    for (int j = 0; j < 4; ++j) {
        int idx4 = tid + j * 256;
        int row  = idx4 >> 5;
        int c4   = (idx4 & 31) * 4;
        int gr   = r0 + row;
        float4 hv = make_float4(0.f, 0.f, 0.f, 0.f);
        float4 cv = make_float4(0.f, 0.f, 0.f, 0.f);
        if (gr < N) {
            hv = *(const float4*)&h[(size_t)gr * D + c4];
            cv = *(const float4*)&c[(size_t)gr * D + c4];
        }
        *(float4*)&hs[row][c4]       = hv;
        *(float4*)&hs[row][128 + c4] = cv;
    }
    __syncthreads();

    const int wave = tid >> 6, lane = tid & 63;
    const int lr    = wave * 8;
    const int rbase = r0 + lr;
    if (rbase >= N) return;

    float a0[8], a1[8];
    #pragma unroll
    for (int r = 0; r < 8; ++r) { a0[r] = a1[r] = 0.f; }

    for (int k4 = 0; k4 < 64; ++k4) {       // K = 256
        float4 hv[8];
        #pragma unroll
        for (int r = 0; r < 8; ++r)
            hv[r] = *(const float4*)&hs[lr + r][k4 * 4];
        #pragma unroll
        for (int kk = 0; kk < 4; ++kk) {
            const int k = k4 * 4 + kk;
            const float w0 = Wn[k * D + lane], w1 = Wn[k * D + 64 + lane];
            #pragma unroll
            for (int r = 0; r < 8; ++r) {
                const float hk = ((const float*)&hv[r])[kk];
                a0[r] = fmaf(hk, w0, a0[r]);
                a1[r] = fmaf(hk, w1, a1[r]);
            }
        }
    }

    const float bn0 = bn[lane], bn1 = bn[64 + lane];
    #pragma unroll
    for (int r = 0; r < 8; ++r) {
        const int gr = rbase + r;
        float v0 = a0[r] + bn0;
        float v1 = a1[r] + bn1;
        float ss = v0 * v0 + v1 * v1;
        #pragma unroll
        for (int off = 32; off >= 1; off >>= 1)
            ss += __shfl_xor(ss, off);      // 64-lane reduce
        const float inv = 1.0f / fmaxf(sqrtf(ss), 1e-12f);
        const float o0 = hs[lr + r][lane]      + fmaxf(v0 * inv, 0.0f);
        const float o1 = hs[lr + r][64 + lane] + fmaxf(v1 * inv, 0.0f);
        if (gr < N) {
            out[(size_t)gr * D + lane]      = o0;
            out[(size_t)gr * D + 64 + lane] = o1;
        }
    }
}

// ---------------------------------------------------------------------------
extern "C" void kernel_launch(void* const* d_in, const int* in_sizes, int n_in,
                              void* d_out, int out_size, void* d_ws, size_t ws_size,
                              hipStream_t stream)
{
    const float* h   = (const float*)d_in[0];
    const int*   src = (const int*)  d_in[1];
    const int*   dst = (const int*)  d_in[2];
    const float* WA  = (const float*)d_in[3];
    const float* bA  = (const float*)d_in[4];
    const float* WB  = (const float*)d_in[5];
    const float* bB  = (const float*)d_in[6];
    const float* Wn  = (const float*)d_in[7];
    const float* bn  = (const float*)d_in[8];

    const int N = in_sizes[0] / D;
    const int E = in_sizes[1];

    // workspace layout (element offsets kept multiples of 4 => 16B aligned)
    const size_t nd     = (size_t)N * D;
    const size_t npad   = (size_t)((N + 4 + 3) / 4) * 4;   // row_ptr: N+1, padded
    float* Ah       = (float*)d_ws;
    float* Bh       = Ah + nd;
    int*   row_ptr  = (int*)(Bh + nd);
    int*   cursor   = row_ptr + npad;
    int*   cnt_buf  = cursor + ((size_t)((N + 3) / 4) * 4);
    int*   edge_src = cnt_buf + ((size_t)((N + 3) / 4) * 4);
    float* c        = (float*)(edge_src + (size_t)((E + 3) / 4) * 4);

    const size_t need_c = (size_t)((char*)(c + nd) - (char*)d_ws);
    if (ws_size < need_c) c = (float*)d_out;   // safe: node_apply stages rows first

    hipMemsetAsync(cnt_buf, 0, (size_t)N * sizeof(int), stream);

    const int nb = (N + 31) / 32;
    gemm_ab<<<nb, 256, 0, stream>>>(h, WA, bA, WB, bB, Ah, Bh, N);

    const int eb = (E + 255) / 256;
    hist_kernel<<<eb, 256, 0, stream>>>(dst, cnt_buf, E);
    scan_kernel<<<1, 1024, 0, stream>>>(cnt_buf, row_ptr, cursor, N, E);
    scatter_kernel<<<eb, 256, 0, stream>>>(src, dst, cursor, edge_src, E);

    node_gather<<<(N + 3) / 4, 256, 0, stream>>>(Ah, Bh, row_ptr, edge_src, c, N);

    node_apply<<<nb, 256, 0, stream>>>(h, c, Wn, bn, (float*)d_out, N);
}

// Round 7
// 433.184 us; speedup vs baseline: 3.0027x; 1.2703x over previous
//
#include <hip/hip_runtime.h>

#define D 128
#define SCAN_EPB 1024   // counters per scan block (256 threads x int4)

// ---------------------------------------------------------------------------
// Kernel 1: Ah = h@WA + bA, Bh = h@WB + bB   (fp32 GEMV-batch, 8 rows/wave)
// ---------------------------------------------------------------------------
__launch_bounds__(256, 2)
__global__ void gemm_ab(const float* __restrict__ h,
                        const float* __restrict__ WA, const float* __restrict__ bA,
                        const float* __restrict__ WB, const float* __restrict__ bB,
                        float* __restrict__ Ah, float* __restrict__ Bh, int N)
{
    __shared__ float hs[32][128];           // 16 KB: 32 rows of h
    const int tid = threadIdx.x;
    const int r0  = blockIdx.x * 32;

    #pragma unroll
    for (int j = 0; j < 4; ++j) {
        int idx4 = tid + j * 256;           // 0..1023 float4 slots
        int row  = idx4 >> 5;               // 32 float4 per row
        int c4   = (idx4 & 31) * 4;
        int gr   = r0 + row;
        float4 v = make_float4(0.f, 0.f, 0.f, 0.f);
        if (gr < N) v = *(const float4*)&h[(size_t)gr * D + c4];
        *(float4*)&hs[row][c4] = v;
    }
    __syncthreads();

    const int wave = tid >> 6, lane = tid & 63;
    const int lr    = wave * 8;
    const int rbase = r0 + lr;
    if (rbase >= N) return;

    float a0[8], a1[8], b0[8], b1[8];
    #pragma unroll
    for (int r = 0; r < 8; ++r) { a0[r] = a1[r] = b0[r] = b1[r] = 0.f; }

    for (int k4 = 0; k4 < 32; ++k4) {
        float4 hv[8];
        #pragma unroll
        for (int r = 0; r < 8; ++r)
            hv[r] = *(const float4*)&hs[lr + r][k4 * 4];
        #pragma unroll
        for (int kk = 0; kk < 4; ++kk) {
            const int k = k4 * 4 + kk;
            const float wa0 = WA[k * D + lane], wa1 = WA[k * D + 64 + lane];
            const float wb0 = WB[k * D + lane], wb1 = WB[k * D + 64 + lane];
            #pragma unroll
            for (int r = 0; r < 8; ++r) {
                const float hk = ((const float*)&hv[r])[kk];
                a0[r] = fmaf(hk, wa0, a0[r]);
                a1[r] = fmaf(hk, wa1, a1[r]);
                b0[r] = fmaf(hk, wb0, b0[r]);
                b1[r] = fmaf(hk, wb1, b1[r]);
            }
        }
    }

    const float biasA0 = bA[lane], biasA1 = bA[64 + lane];
    const float biasB0 = bB[lane], biasB1 = bB[64 + lane];
    #pragma unroll
    for (int r = 0; r < 8; ++r) {
        const int gr = rbase + r;
        if (gr < N) {
            Ah[(size_t)gr * D + lane]      = a0[r] + biasA0;
            Ah[(size_t)gr * D + 64 + lane] = a1[r] + biasA1;
            Bh[(size_t)gr * D + lane]      = b0[r] + biasB0;
            Bh[(size_t)gr * D + 64 + lane] = b1[r] + biasB1;
        }
    }
}

// ---------------------------------------------------------------------------
// CSR build: histogram -> 3-pass multi-block exclusive scan -> scatter
// ---------------------------------------------------------------------------
__launch_bounds__(256)
__global__ void hist_kernel(const int* __restrict__ dst,
                            int* __restrict__ counters, int E)
{
    const int e = blockIdx.x * 256 + threadIdx.x;
    if (e < E) atomicAdd(&counters[dst[e]], 1);
}

// pass1: per-block sum of SCAN_EPB counters
__launch_bounds__(256)
__global__ void scan_pass1(const int* __restrict__ counters,
                           int* __restrict__ block_sums, int N)
{
    const int b = blockIdx.x, t = threadIdx.x;
    const int base = b * SCAN_EPB + t * 4;
    int s = 0;
    if (base + 3 < N) {
        const int4 v = *(const int4*)&counters[base];
        s = v.x + v.y + v.z + v.w;
    } else {
        #pragma unroll
        for (int i = 0; i < 4; ++i) if (base + i < N) s += counters[base + i];
    }
    #pragma unroll
    for (int off = 32; off >= 1; off >>= 1) s += __shfl_xor(s, off);
    __shared__ int ws[4];
    const int wave = t >> 6, lane = t & 63;
    if (lane == 0) ws[wave] = s;
    __syncthreads();
    if (t == 0) block_sums[b] = ws[0] + ws[1] + ws[2] + ws[3];
}

// pass2: single-block exclusive scan of block sums (NB <= 1024)
__launch_bounds__(1024)
__global__ void scan_pass2(const int* __restrict__ block_sums,
                           int* __restrict__ block_offs, int NB)
{
    __shared__ int part[1024];
    const int t = threadIdx.x;
    part[t] = (t < NB) ? block_sums[t] : 0;
    __syncthreads();
    for (int off = 1; off < 1024; off <<= 1) {   // Hillis-Steele inclusive
        int v = (t >= off) ? part[t - off] : 0;
        __syncthreads();
        part[t] += v;
        __syncthreads();
    }
    if (t < NB) block_offs[t] = (t == 0) ? 0 : part[t - 1];
}

// pass3: in-block exclusive scan + global offset -> row_ptr & cursor
__launch_bounds__(256)
__global__ void scan_pass3(const int* __restrict__ counters,
                           const int* __restrict__ block_offs,
                           int* __restrict__ row_ptr, int* __restrict__ cursor,
                           int N, int E)
{
    const int b = blockIdx.x, t = threadIdx.x;
    const int wave = t >> 6, lane = t & 63;
    const int base = b * SCAN_EPB + t * 4;

    int4 v = make_int4(0, 0, 0, 0);
    if (base + 3 < N) {
        v = *(const int4*)&counters[base];
    } else {
        if (base + 0 < N) v.x = counters[base + 0];
        if (base + 1 < N) v.y = counters[base + 1];
        if (base + 2 < N) v.z = counters[base + 2];
        if (base + 3 < N) v.w = counters[base + 3];
    }
    const int tsum = v.x + v.y + v.z + v.w;

    int x = tsum;                           // inclusive wave scan
    #pragma unroll
    for (int off = 1; off < 64; off <<= 1) {
        int y = __shfl_up(x, off);
        if (lane >= off) x += y;
    }
    __shared__ int wsum[4];
    if (lane == 63) wsum[wave] = x;
    __syncthreads();
    int woff = 0;
    #pragma unroll
    for (int w = 0; w < 4; ++w) woff += (w < wave) ? wsum[w] : 0;

    const int p0 = block_offs[b] + woff + (x - tsum);
    const int p1 = p0 + v.x;
    const int p2 = p1 + v.y;
    const int p3 = p2 + v.z;
    if (base + 0 < N) { row_ptr[base + 0] = p0; cursor[base + 0] = p0; }
    if (base + 1 < N) { row_ptr[base + 1] = p1; cursor[base + 1] = p1; }
    if (base + 2 < N) { row_ptr[base + 2] = p2; cursor[base + 2] = p2; }
    if (base + 3 < N) { row_ptr[base + 3] = p3; cursor[base + 3] = p3; }
    if (b == 0 && t == 0) row_ptr[N] = E;
}

__launch_bounds__(256)
__global__ void scatter_kernel(const int* __restrict__ src,
                               const int* __restrict__ dst,
                               int* __restrict__ cursor,
                               int* __restrict__ edge_src, int E)
{
    const int e = blockIdx.x * 256 + threadIdx.x;
    if (e < E) {
        const int pos = atomicAdd(&cursor[dst[e]], 1);
        edge_src[pos] = src[e];
    }
}

// ---------------------------------------------------------------------------
// Kernel 2': per-dst-node gather + gated-message max-reduce, atomic-free.
// One wave per dst node; lane owns 2 features (float2). m init 0 implements
// both relu(msg) (msg<=0 never wins) and the zero-in-degree clamp.
// ---------------------------------------------------------------------------
__launch_bounds__(256)
__global__ void node_gather(const float* __restrict__ Ah,
                            const float* __restrict__ Bh,
                            const int* __restrict__ row_ptr,
                            const int* __restrict__ edge_src,
                            float* __restrict__ c, int N)
{
    const int wave = threadIdx.x >> 6, lane = threadIdx.x & 63;
    const int d = blockIdx.x * 4 + wave;
    if (d >= N) return;

    const int beg = row_ptr[d], end = row_ptr[d + 1];
    const float2 bd = *(const float2*)&Bh[(size_t)d * D + lane * 2];
    float m0 = 0.f, m1 = 0.f;

    for (int base = beg; base < end; base += 64) {
        const int cnt = min(64, end - base);
        const int sv = (lane < cnt) ? edge_src[base + lane] : 0;
        for (int i = 0; i < cnt; ++i) {
            const int s = __shfl(sv, i);
            const float2 bs = *(const float2*)&Bh[(size_t)s * D + lane * 2];
            const float2 as = *(const float2*)&Ah[(size_t)s * D + lane * 2];
            const float e0 = bs.x + bd.x, e1 = bs.y + bd.y;
            const float p0 = as.x / (1.f + __expf(-e0));
            const float p1 = as.y / (1.f + __expf(-e1));
            m0 = fmaxf(m0, p0);
            m1 = fmaxf(m1, p1);
        }
    }
    float2 o; o.x = m0; o.y = m1;
    *(float2*)&c[(size_t)d * D + lane * 2] = o;
}

// ---------------------------------------------------------------------------
// Kernel 3: bundle = [h|c]@Wn + bn; L2-normalize rows; relu; residual add.
// ---------------------------------------------------------------------------
__launch_bounds__(256, 2)
__global__ void node_apply(const float* __restrict__ h,
                           const float* __restrict__ c,
                           const float* __restrict__ Wn,
                           const float* __restrict__ bn,
                           float* __restrict__ out, int N)
{
    __shared__ float hs[32][256];           // 32 KB: [h | c] per row
    const int tid = threadIdx.x;
    const int r0  = blockIdx.x * 32;

    #pragma unroll
    for (int j = 0; j < 4; ++j) {
        int idx4 = tid + j * 256;
        int row  = idx4 >> 5;
        int c4   = (idx4 & 31) * 4;
        int gr   = r0 + row;
        float4 hv = make_float4(0.f, 0.f, 0.f, 0.f);
        float4 cv = make_float4(0.f, 0.f, 0.f, 0.f);
        if (gr < N) {
            hv = *(const float4*)&h[(size_t)gr * D + c4];
            cv = *(const float4*)&c[(size_t)gr * D + c4];
        }
        *(float4*)&hs[row][c4]       = hv;
        *(float4*)&hs[row][128 + c4] = cv;
    }
    __syncthreads();

    const int wave = tid >> 6, lane = tid & 63;
    const int lr    = wave * 8;
    const int rbase = r0 + lr;
    if (rbase >= N) return;

    float a0[8], a1[8];
    #pragma unroll
    for (int r = 0; r < 8; ++r) { a0[r] = a1[r] = 0.f; }

    for (int k4 = 0; k4 < 64; ++k4) {       // K = 256
        float4 hv[8];
        #pragma unroll
        for (int r = 0; r < 8; ++r)
            hv[r] = *(const float4*)&hs[lr + r][k4 * 4];
        #pragma unroll
        for (int kk = 0; kk < 4; ++kk) {
            const int k = k4 * 4 + kk;
            const float w0 = Wn[k * D + lane], w1 = Wn[k * D + 64 + lane];
            #pragma unroll
            for (int r = 0; r < 8; ++r) {
                const float hk = ((const float*)&hv[r])[kk];
                a0[r] = fmaf(hk, w0, a0[r]);
                a1[r] = fmaf(hk, w1, a1[r]);
            }
        }
    }

    const float bn0 = bn[lane], bn1 = bn[64 + lane];
    #pragma unroll
    for (int r = 0; r < 8; ++r) {
        const int gr = rbase + r;
        float v0 = a0[r] + bn0;
        float v1 = a1[r] + bn1;
        float ss = v0 * v0 + v1 * v1;
        #pragma unroll
        for (int off = 32; off >= 1; off >>= 1)
            ss += __shfl_xor(ss, off);      // 64-lane reduce
        const float inv = 1.0f / fmaxf(sqrtf(ss), 1e-12f);
        const float o0 = hs[lr + r][lane]      + fmaxf(v0 * inv, 0.0f);
        const float o1 = hs[lr + r][64 + lane] + fmaxf(v1 * inv, 0.0f);
        if (gr < N) {
            out[(size_t)gr * D + lane]      = o0;
            out[(size_t)gr * D + 64 + lane] = o1;
        }
    }
}

// ---------------------------------------------------------------------------
extern "C" void kernel_launch(void* const* d_in, const int* in_sizes, int n_in,
                              void* d_out, int out_size, void* d_ws, size_t ws_size,
                              hipStream_t stream)
{
    const float* h   = (const float*)d_in[0];
    const int*   src = (const int*)  d_in[1];
    const int*   dst = (const int*)  d_in[2];
    const float* WA  = (const float*)d_in[3];
    const float* bA  = (const float*)d_in[4];
    const float* WB  = (const float*)d_in[5];
    const float* bB  = (const float*)d_in[6];
    const float* Wn  = (const float*)d_in[7];
    const float* bn  = (const float*)d_in[8];

    const int N = in_sizes[0] / D;
    const int E = in_sizes[1];

    // workspace layout (element offsets kept multiples of 4 => 16B aligned)
    const size_t nd   = (size_t)N * D;
    const size_t npad = (size_t)((N + 4 + 3) / 4) * 4;     // row_ptr: N+1, padded
    const size_t n4   = (size_t)((N + 3) / 4) * 4;
    float* Ah         = (float*)d_ws;
    float* Bh         = Ah + nd;
    int*   row_ptr    = (int*)(Bh + nd);
    int*   cursor     = row_ptr + npad;
    int*   cnt_buf    = cursor + n4;
    int*   block_sums = cnt_buf + n4;
    int*   block_offs = block_sums + 1024;
    int*   edge_src   = block_offs + 1024;
    float* c          = (float*)(edge_src + (size_t)((E + 3) / 4) * 4);

    const size_t need_c = (size_t)((char*)(c + nd) - (char*)d_ws);
    if (ws_size < need_c) c = (float*)d_out;   // safe: node_apply stages rows first

    hipMemsetAsync(cnt_buf, 0, (size_t)N * sizeof(int), stream);

    const int nb = (N + 31) / 32;
    gemm_ab<<<nb, 256, 0, stream>>>(h, WA, bA, WB, bB, Ah, Bh, N);

    const int eb = (E + 255) / 256;
    const int NB = (N + SCAN_EPB - 1) / SCAN_EPB;
    hist_kernel<<<eb, 256, 0, stream>>>(dst, cnt_buf, E);
    scan_pass1<<<NB, 256, 0, stream>>>(cnt_buf, block_sums, N);
    scan_pass2<<<1, 1024, 0, stream>>>(block_sums, block_offs, NB);
    scan_pass3<<<NB, 256, 0, stream>>>(cnt_buf, block_offs, row_ptr, cursor, N, E);
    scatter_kernel<<<eb, 256, 0, stream>>>(src, dst, cursor, edge_src, E);

    node_gather<<<(N + 3) / 4, 256, 0, stream>>>(Ah, Bh, row_ptr, edge_src, c, N);

    node_apply<<<nb, 256, 0, stream>>>(h, c, Wn, bn, (float*)d_out, N);
}

// Round 9
// 333.054 us; speedup vs baseline: 3.9054x; 1.3006x over previous
//
#include <hip/hip_runtime.h>

#define D 128
#define SCAN_EPB 1024   // counters per scan block (256 threads x int4)

typedef float f32x4 __attribute__((ext_vector_type(4)));
typedef short s16x8 __attribute__((ext_vector_type(8)));

__device__ __forceinline__ unsigned short f2bf(float f) {
    union { float f; unsigned u; } v; v.f = f;
    unsigned r = v.u + 0x7FFF + ((v.u >> 16) & 1);   // RNE
    return (unsigned short)(r >> 16);
}
__device__ __forceinline__ float bf2f(unsigned short u) {
    union { unsigned u; float f; } v; v.u = (unsigned)u << 16;
    return v.f;
}
__device__ __forceinline__ s16x8 pack2(float4 lo, float4 hi) {
    s16x8 o;
    o[0] = (short)f2bf(lo.x); o[1] = (short)f2bf(lo.y);
    o[2] = (short)f2bf(lo.z); o[3] = (short)f2bf(lo.w);
    o[4] = (short)f2bf(hi.x); o[5] = (short)f2bf(hi.y);
    o[6] = (short)f2bf(hi.z); o[7] = (short)f2bf(hi.w);
    return o;
}

// ---------------------------------------------------------------------------
// Prep: transpose weights to [col][k] bf16 once; fuse biases of A|B.
// ---------------------------------------------------------------------------
__launch_bounds__(256)
__global__ void prep_weights(const float* __restrict__ WA, const float* __restrict__ bA,
                             const float* __restrict__ WB, const float* __restrict__ bB,
                             const float* __restrict__ Wn,
                             short* __restrict__ Wab_t, short* __restrict__ Wn_t,
                             float* __restrict__ bias_ab)
{
    const int b = blockIdx.x, t = threadIdx.x;
    if (b < 256) {                                   // Wab_t col b, K=128
        if (t < 128)
            Wab_t[b * 128 + t] = (short)f2bf(b < 128 ? WA[t * 128 + b]
                                                     : WB[t * 128 + (b - 128)]);
        if (t == 128) bias_ab[b] = (b < 128) ? bA[b] : bB[b - 128];
    } else {                                         // Wn_t col (b-256), K=256
        const int col = b - 256;
        Wn_t[col * 256 + t] = (short)f2bf(Wn[t * 128 + col]);
    }
}

// ---------------------------------------------------------------------------
// Kernel 1: AB[row][0:128]=h@WA+bA, AB[row][128:256]=h@WB+bB  (bf16 MFMA)
// Wave = 16 rows x 256 cols. A/B frags share one k-bijection (layout-robust);
// C/D mapping col=lane&15, row=4*(lane>>4)+reg is the HW-measured one.
// ---------------------------------------------------------------------------
__launch_bounds__(256)
__global__ void gemm_ab_mfma(const float* __restrict__ h,
                             const short* __restrict__ Wab_t,
                             const float* __restrict__ bias_ab,
                             short* __restrict__ AB, int N)
{
    const int tid = threadIdx.x, w = tid >> 6, l = tid & 63;
    const int rbase = blockIdx.x * 64 + w * 16;
    if (rbase >= N) return;                          // N%16==0: waves all-or-nothing
    const int g = l >> 4, r = l & 15;

    const float* hrow = h + (size_t)(rbase + r) * D + g * 8;
    s16x8 af[4];
    #pragma unroll
    for (int s = 0; s < 4; ++s) {
        float4 lo = *(const float4*)(hrow + s * 32);
        float4 hi = *(const float4*)(hrow + s * 32 + 4);
        af[s] = pack2(lo, hi);
    }

    f32x4 acc[16];
    #pragma unroll
    for (int t = 0; t < 16; ++t) acc[t] = (f32x4){0.f, 0.f, 0.f, 0.f};

    #pragma unroll
    for (int t = 0; t < 16; ++t) {
        const short* wc = Wab_t + (size_t)(t * 16 + r) * 128 + g * 8;
        #pragma unroll
        for (int s = 0; s < 4; ++s) {
            s16x8 bf = *(const s16x8*)(wc + s * 32);
            acc[t] = __builtin_amdgcn_mfma_f32_16x16x32_bf16(af[s], bf, acc[t], 0, 0, 0);
        }
    }

    #pragma unroll
    for (int t = 0; t < 16; ++t) {
        const int col = t * 16 + r;
        const float bb = bias_ab[col];
        #pragma unroll
        for (int q = 0; q < 4; ++q) {
            const int orow = rbase + g * 4 + q;
            AB[(size_t)orow * 256 + col] = (short)f2bf(acc[t][q] + bb);
        }
    }
}

// ---------------------------------------------------------------------------
// CSR build: histogram -> 3-pass multi-block exclusive scan -> scatter
// ---------------------------------------------------------------------------
__launch_bounds__(256)
__global__ void hist_kernel(const int* __restrict__ dst,
                            int* __restrict__ counters, int E)
{
    const int e = blockIdx.x * 256 + threadIdx.x;
    if (e < E) atomicAdd(&counters[dst[e]], 1);
}

__launch_bounds__(256)
__global__ void scan_pass1(const int* __restrict__ counters,
                           int* __restrict__ block_sums, int N)
{
    const int b = blockIdx.x, t = threadIdx.x;
    const int base = b * SCAN_EPB + t * 4;
    int s = 0;
    if (base + 3 < N) {
        const int4 v = *(const int4*)&counters[base];
        s = v.x + v.y + v.z + v.w;
    } else {
        #pragma unroll
        for (int i = 0; i < 4; ++i) if (base + i < N) s += counters[base + i];
    }
    #pragma unroll
    for (int off = 32; off >= 1; off >>= 1) s += __shfl_xor(s, off);
    __shared__ int ws[4];
    const int wave = t >> 6, lane = t & 63;
    if (lane == 0) ws[wave] = s;
    __syncthreads();
    if (t == 0) block_sums[b] = ws[0] + ws[1] + ws[2] + ws[3];
}

__launch_bounds__(1024)
__global__ void scan_pass2(const int* __restrict__ block_sums,
                           int* __restrict__ block_offs, int NB)
{
    __shared__ int part[1024];
    const int t = threadIdx.x;
    part[t] = (t < NB) ? block_sums[t] : 0;
    __syncthreads();
    for (int off = 1; off < 1024; off <<= 1) {
        int v = (t >= off) ? part[t - off] : 0;
        __syncthreads();
        part[t] += v;
        __syncthreads();
    }
    if (t < NB) block_offs[t] = (t == 0) ? 0 : part[t - 1];
}

__launch_bounds__(256)
__global__ void scan_pass3(const int* __restrict__ counters,
                           const int* __restrict__ block_offs,
                           int* __restrict__ row_ptr, int* __restrict__ cursor,
                           int N, int E)
{
    const int b = blockIdx.x, t = threadIdx.x;
    const int wave = t >> 6, lane = t & 63;
    const int base = b * SCAN_EPB + t * 4;

    int4 v = make_int4(0, 0, 0, 0);
    if (base + 3 < N) {
        v = *(const int4*)&counters[base];
    } else {
        if (base + 0 < N) v.x = counters[base + 0];
        if (base + 1 < N) v.y = counters[base + 1];
        if (base + 2 < N) v.z = counters[base + 2];
        if (base + 3 < N) v.w = counters[base + 3];
    }
    const int tsum = v.x + v.y + v.z + v.w;

    int x = tsum;
    #pragma unroll
    for (int off = 1; off < 64; off <<= 1) {
        int y = __shfl_up(x, off);
        if (lane >= off) x += y;
    }
    __shared__ int wsum[4];
    if (lane == 63) wsum[wave] = x;
    __syncthreads();
    int woff = 0;
    #pragma unroll
    for (int w = 0; w < 4; ++w) woff += (w < wave) ? wsum[w] : 0;

    const int p0 = block_offs[b] + woff + (x - tsum);
    const int p1 = p0 + v.x;
    const int p2 = p1 + v.y;
    const int p3 = p2 + v.z;
    if (base + 0 < N) { row_ptr[base + 0] = p0; cursor[base + 0] = p0; }
    if (base + 1 < N) { row_ptr[base + 1] = p1; cursor[base + 1] = p1; }
    if (base + 2 < N) { row_ptr[base + 2] = p2; cursor[base + 2] = p2; }
    if (base + 3 < N) { row_ptr[base + 3] = p3; cursor[base + 3] = p3; }
    if (b == 0 && t == 0) row_ptr[N] = E;
}

__launch_bounds__(256)
__global__ void scatter_kernel(const int* __restrict__ src,
                               const int* __restrict__ dst,
                               int* __restrict__ cursor,
                               int* __restrict__ edge_src, int E)
{
    const int e = blockIdx.x * 256 + threadIdx.x;
    if (e < E) {
        const int pos = atomicAdd(&cursor[dst[e]], 1);
        edge_src[pos] = src[e];
    }
}

// ---------------------------------------------------------------------------
// Kernel 2: per-dst-node gather + gated-message max-reduce (bf16 AB rows).
// One wave per dst node; lane owns 2 features. m init 0 = relu + 0-indeg clamp.
// ---------------------------------------------------------------------------
__launch_bounds__(256)
__global__ void node_gather(const short* __restrict__ AB,
                            const int* __restrict__ row_ptr,
                            const int* __restrict__ edge_src,
                            short* __restrict__ c, int N)
{
    const int wave = threadIdx.x >> 6, lane = threadIdx.x & 63;
    const int d = blockIdx.x * 4 + wave;
    if (d >= N) return;

    const int beg = row_ptr[d], end = row_ptr[d + 1];
    const unsigned bdp = *(const unsigned*)&AB[(size_t)d * 256 + 128 + lane * 2];
    const float bd0 = bf2f((unsigned short)(bdp & 0xFFFF));
    const float bd1 = bf2f((unsigned short)(bdp >> 16));
    float m0 = 0.f, m1 = 0.f;

    for (int base = beg; base < end; base += 64) {
        const int cnt = min(64, end - base);
        const int sv = (lane < cnt) ? edge_src[base + lane] : 0;
        for (int i = 0; i < cnt; ++i) {
            const int s = __shfl(sv, i);
            const size_t sb = (size_t)s * 256 + lane * 2;
            const unsigned asp = *(const unsigned*)&AB[sb];
            const unsigned bsp = *(const unsigned*)&AB[sb + 128];
            const float e0 = bf2f((unsigned short)(bsp & 0xFFFF)) + bd0;
            const float e1 = bf2f((unsigned short)(bsp >> 16)) + bd1;
            const float p0 = bf2f((unsigned short)(asp & 0xFFFF)) / (1.f + __expf(-e0));
            const float p1 = bf2f((unsigned short)(asp >> 16)) / (1.f + __expf(-e1));
            m0 = fmaxf(m0, p0);
            m1 = fmaxf(m1, p1);
        }
    }
    const unsigned packed = (unsigned)f2bf(m0) | ((unsigned)f2bf(m1) << 16);
    *(unsigned*)&c[(size_t)d * D + lane * 2] = packed;
}

// ---------------------------------------------------------------------------
// Kernel 3: bundle = [h|c]@Wn + bn (bf16 MFMA, K=256); L2-norm; relu; residual.
// ---------------------------------------------------------------------------
__launch_bounds__(256)
__global__ void node_apply_mfma(const float* __restrict__ h,
                                const short* __restrict__ c,
                                const short* __restrict__ Wn_t,
                                const float* __restrict__ bn,
                                float* __restrict__ out, int N)
{
    const int tid = threadIdx.x, w = tid >> 6, l = tid & 63;
    const int rbase = blockIdx.x * 64 + w * 16;
    if (rbase >= N) return;
    const int g = l >> 4, r = l & 15;

    const float* hrow = h + (size_t)(rbase + r) * D + g * 8;
    const short* crow = c + (size_t)(rbase + r) * D + g * 8;

    f32x4 acc[8];
    #pragma unroll
    for (int t = 0; t < 8; ++t) acc[t] = (f32x4){0.f, 0.f, 0.f, 0.f};

    #pragma unroll
    for (int s = 0; s < 8; ++s) {
        s16x8 af;
        if (s < 4) {
            float4 lo = *(const float4*)(hrow + s * 32);
            float4 hi = *(const float4*)(hrow + s * 32 + 4);
            af = pack2(lo, hi);
        } else {
            af = *(const s16x8*)(crow + (s - 4) * 32);
        }
        #pragma unroll
        for (int t = 0; t < 8; ++t) {
            s16x8 bf = *(const s16x8*)(Wn_t + (size_t)(t * 16 + r) * 256 + s * 32 + g * 8);
            acc[t] = __builtin_amdgcn_mfma_f32_16x16x32_bf16(af, bf, acc[t], 0, 0, 0);
        }
    }

    float v[8][4];
    float ss[4] = {0.f, 0.f, 0.f, 0.f};
    #pragma unroll
    for (int t = 0; t < 8; ++t) {
        const float bb = bn[t * 16 + r];
        #pragma unroll
        for (int q = 0; q < 4; ++q) {
            const float x = acc[t][q] + bb;
            v[t][q] = x;
            ss[q] += x * x;
        }
    }
    #pragma unroll
    for (int m = 1; m < 16; m <<= 1) {      // reduce across the 16 lanes of a group
        #pragma unroll
        for (int q = 0; q < 4; ++q) ss[q] += __shfl_xor(ss[q], m);
    }
    float inv[4];
    #pragma unroll
    for (int q = 0; q < 4; ++q) inv[q] = 1.0f / fmaxf(sqrtf(ss[q]), 1e-12f);

    #pragma unroll
    for (int t = 0; t < 8; ++t) {
        const int col = t * 16 + r;
        #pragma unroll
        for (int q = 0; q < 4; ++q) {
            const size_t o = (size_t)(rbase + g * 4 + q) * D + col;
            out[o] = h[o] + fmaxf(v[t][q] * inv[q], 0.0f);
        }
    }
}

// ---------------------------------------------------------------------------
extern "C" void kernel_launch(void* const* d_in, const int* in_sizes, int n_in,
                              void* d_out, int out_size, void* d_ws, size_t ws_size,
                              hipStream_t stream)
{
    const float* h   = (const float*)d_in[0];
    const int*   src = (const int*)  d_in[1];
    const int*   dst = (const int*)  d_in[2];
    const float* WA  = (const float*)d_in[3];
    const float* bA  = (const float*)d_in[4];
    const float* WB  = (const float*)d_in[5];
    const float* bB  = (const float*)d_in[6];
    const float* Wn  = (const float*)d_in[7];
    const float* bn  = (const float*)d_in[8];

    const int N = in_sizes[0] / D;
    const int E = in_sizes[1];

    // workspace layout (~42 MB; rounds 6-7 prove ws >= ~55 MB)
    const size_t npad = (size_t)((N + 4 + 3) / 4) * 4;
    const size_t n4   = (size_t)((N + 3) / 4) * 4;
    short* AB         = (short*)d_ws;                 // [N][256] bf16
    short* c_bf       = AB + (size_t)N * 256;         // [N][128] bf16
    short* Wab_t      = c_bf + (size_t)N * D;         // [256][128] bf16
    short* Wn_t       = Wab_t + 256 * 128;            // [128][256] bf16
    float* bias_ab    = (float*)(Wn_t + 128 * 256);   // [256]
    int*   row_ptr    = (int*)(bias_ab + 256);
    int*   cursor     = row_ptr + npad;
    int*   cnt_buf    = cursor + n4;
    int*   block_sums = cnt_buf + n4;
    int*   block_offs = block_sums + 1024;
    int*   edge_src   = block_offs + 1024;

    hipMemsetAsync(cnt_buf, 0, (size_t)N * sizeof(int), stream);

    prep_weights<<<384, 256, 0, stream>>>(WA, bA, WB, bB, Wn, Wab_t, Wn_t, bias_ab);

    const int gb = (N + 63) / 64;
    gemm_ab_mfma<<<gb, 256, 0, stream>>>(h, Wab_t, bias_ab, AB, N);

    const int eb = (E + 255) / 256;
    const int NB = (N + SCAN_EPB - 1) / SCAN_EPB;
    hist_kernel<<<eb, 256, 0, stream>>>(dst, cnt_buf, E);
    scan_pass1<<<NB, 256, 0, stream>>>(cnt_buf, block_sums, N);
    scan_pass2<<<1, 1024, 0, stream>>>(block_sums, block_offs, NB);
    scan_pass3<<<NB, 256, 0, stream>>>(cnt_buf, block_offs, row_ptr, cursor, N, E);
    scatter_kernel<<<eb, 256, 0, stream>>>(src, dst, cursor, edge_src, E);

    node_gather<<<(N + 3) / 4, 256, 0, stream>>>(AB, row_ptr, edge_src, c_bf, N);

    node_apply_mfma<<<gb, 256, 0, stream>>>(h, c_bf, Wn_t, bn, (float*)d_out, N);
}

// Round 10
// 324.517 us; speedup vs baseline: 4.0082x; 1.0263x over previous
//
#include <hip/hip_runtime.h>

#define D 128
#define SCAN_EPB 1024   // counters per scan block (256 threads x int4)

typedef float f32x4 __attribute__((ext_vector_type(4)));
typedef short s16x8 __attribute__((ext_vector_type(8)));

__device__ __forceinline__ unsigned short f2bf(float f) {
    union { float f; unsigned u; } v; v.f = f;
    unsigned r = v.u + 0x7FFF + ((v.u >> 16) & 1);   // RNE
    return (unsigned short)(r >> 16);
}
__device__ __forceinline__ float bf2f(unsigned short u) {
    union { unsigned u; float f; } v; v.u = (unsigned)u << 16;
    return v.f;
}
__device__ __forceinline__ s16x8 pack2(float4 lo, float4 hi) {
    s16x8 o;
    o[0] = (short)f2bf(lo.x); o[1] = (short)f2bf(lo.y);
    o[2] = (short)f2bf(lo.z); o[3] = (short)f2bf(lo.w);
    o[4] = (short)f2bf(hi.x); o[5] = (short)f2bf(hi.y);
    o[6] = (short)f2bf(hi.z); o[7] = (short)f2bf(hi.w);
    return o;
}

// ---------------------------------------------------------------------------
// Prep: transpose weights to [col][k] bf16 once; fuse biases of A|B.
// ---------------------------------------------------------------------------
__launch_bounds__(256)
__global__ void prep_weights(const float* __restrict__ WA, const float* __restrict__ bA,
                             const float* __restrict__ WB, const float* __restrict__ bB,
                             const float* __restrict__ Wn,
                             short* __restrict__ Wab_t, short* __restrict__ Wn_t,
                             float* __restrict__ bias_ab)
{
    const int b = blockIdx.x, t = threadIdx.x;
    if (b < 256) {                                   // Wab_t col b, K=128
        if (t < 128)
            Wab_t[b * 128 + t] = (short)f2bf(b < 128 ? WA[t * 128 + b]
                                                     : WB[t * 128 + (b - 128)]);
        if (t == 128) bias_ab[b] = (b < 128) ? bA[b] : bB[b - 128];
    } else {                                         // Wn_t col (b-256), K=256
        const int col = b - 256;
        Wn_t[col * 256 + t] = (short)f2bf(Wn[t * 128 + col]);
    }
}

// ---------------------------------------------------------------------------
// Kernel 1: AB[row][0:128]=h@WA+bA, AB[row][128:256]=h@WB+bB  (bf16 MFMA)
// ---------------------------------------------------------------------------
__launch_bounds__(256)
__global__ void gemm_ab_mfma(const float* __restrict__ h,
                             const short* __restrict__ Wab_t,
                             const float* __restrict__ bias_ab,
                             short* __restrict__ AB, int N)
{
    const int tid = threadIdx.x, w = tid >> 6, l = tid & 63;
    const int rbase = blockIdx.x * 64 + w * 16;
    if (rbase >= N) return;                          // N%16==0: waves all-or-nothing
    const int g = l >> 4, r = l & 15;

    const float* hrow = h + (size_t)(rbase + r) * D + g * 8;
    s16x8 af[4];
    #pragma unroll
    for (int s = 0; s < 4; ++s) {
        float4 lo = *(const float4*)(hrow + s * 32);
        float4 hi = *(const float4*)(hrow + s * 32 + 4);
        af[s] = pack2(lo, hi);
    }

    f32x4 acc[16];
    #pragma unroll
    for (int t = 0; t < 16; ++t) acc[t] = (f32x4){0.f, 0.f, 0.f, 0.f};

    #pragma unroll
    for (int t = 0; t < 16; ++t) {
        const short* wc = Wab_t + (size_t)(t * 16 + r) * 128 + g * 8;
        #pragma unroll
        for (int s = 0; s < 4; ++s) {
            s16x8 bf = *(const s16x8*)(wc + s * 32);
            acc[t] = __builtin_amdgcn_mfma_f32_16x16x32_bf16(af[s], bf, acc[t], 0, 0, 0);
        }
    }

    #pragma unroll
    for (int t = 0; t < 16; ++t) {
        const int col = t * 16 + r;
        const float bb = bias_ab[col];
        #pragma unroll
        for (int q = 0; q < 4; ++q) {
            const int orow = rbase + g * 4 + q;
            AB[(size_t)orow * 256 + col] = (short)f2bf(acc[t][q] + bb);
        }
    }
}

// ---------------------------------------------------------------------------
// CSR build: histogram -> 3-pass multi-block exclusive scan -> scatter
// ---------------------------------------------------------------------------
__launch_bounds__(256)
__global__ void hist_kernel(const int* __restrict__ dst,
                            int* __restrict__ counters, int E)
{
    const int e = blockIdx.x * 256 + threadIdx.x;
    if (e < E) atomicAdd(&counters[dst[e]], 1);
}

__launch_bounds__(256)
__global__ void scan_pass1(const int* __restrict__ counters,
                           int* __restrict__ block_sums, int N)
{
    const int b = blockIdx.x, t = threadIdx.x;
    const int base = b * SCAN_EPB + t * 4;
    int s = 0;
    if (base + 3 < N) {
        const int4 v = *(const int4*)&counters[base];
        s = v.x + v.y + v.z + v.w;
    } else {
        #pragma unroll
        for (int i = 0; i < 4; ++i) if (base + i < N) s += counters[base + i];
    }
    #pragma unroll
    for (int off = 32; off >= 1; off >>= 1) s += __shfl_xor(s, off);
    __shared__ int ws[4];
    const int wave = t >> 6, lane = t & 63;
    if (lane == 0) ws[wave] = s;
    __syncthreads();
    if (t == 0) block_sums[b] = ws[0] + ws[1] + ws[2] + ws[3];
}

__launch_bounds__(1024)
__global__ void scan_pass2(const int* __restrict__ block_sums,
                           int* __restrict__ block_offs, int NB)
{
    __shared__ int part[1024];
    const int t = threadIdx.x;
    part[t] = (t < NB) ? block_sums[t] : 0;
    __syncthreads();
    for (int off = 1; off < 1024; off <<= 1) {
        int v = (t >= off) ? part[t - off] : 0;
        __syncthreads();
        part[t] += v;
        __syncthreads();
    }
    if (t < NB) block_offs[t] = (t == 0) ? 0 : part[t - 1];
}

__launch_bounds__(256)
__global__ void scan_pass3(const int* __restrict__ counters,
                           const int* __restrict__ block_offs,
                           int* __restrict__ row_ptr, int* __restrict__ cursor,
                           int N, int E)
{
    const int b = blockIdx.x, t = threadIdx.x;
    const int wave = t >> 6, lane = t & 63;
    const int base = b * SCAN_EPB + t * 4;

    int4 v = make_int4(0, 0, 0, 0);
    if (base + 3 < N) {
        v = *(const int4*)&counters[base];
    } else {
        if (base + 0 < N) v.x = counters[base + 0];
        if (base + 1 < N) v.y = counters[base + 1];
        if (base + 2 < N) v.z = counters[base + 2];
        if (base + 3 < N) v.w = counters[base + 3];
    }
    const int tsum = v.x + v.y + v.z + v.w;

    int x = tsum;
    #pragma unroll
    for (int off = 1; off < 64; off <<= 1) {
        int y = __shfl_up(x, off);
        if (lane >= off) x += y;
    }
    __shared__ int wsum[4];
    if (lane == 63) wsum[wave] = x;
    __syncthreads();
    int woff = 0;
    #pragma unroll
    for (int w = 0; w < 4; ++w) woff += (w < wave) ? wsum[w] : 0;

    const int p0 = block_offs[b] + woff + (x - tsum);
    const int p1 = p0 + v.x;
    const int p2 = p1 + v.y;
    const int p3 = p2 + v.z;
    if (base + 0 < N) { row_ptr[base + 0] = p0; cursor[base + 0] = p0; }
    if (base + 1 < N) { row_ptr[base + 1] = p1; cursor[base + 1] = p1; }
    if (base + 2 < N) { row_ptr[base + 2] = p2; cursor[base + 2] = p2; }
    if (base + 3 < N) { row_ptr[base + 3] = p3; cursor[base + 3] = p3; }
    if (b == 0 && t == 0) row_ptr[N] = E;
}

__launch_bounds__(256)
__global__ void scatter_kernel(const int* __restrict__ src,
                               const int* __restrict__ dst,
                               int* __restrict__ cursor,
                               int* __restrict__ edge_src, int E)
{
    const int e = blockIdx.x * 256 + threadIdx.x;
    if (e < E) {
        const int pos = atomicAdd(&cursor[dst[e]], 1);
        edge_src[pos] = src[e];
    }
}

// ---------------------------------------------------------------------------
// Kernel 2: per-dst-node gather + gated-message max-reduce (bf16 AB rows).
// VALU-lean: fast divide (v_rcp), shift-only bf16 unpack, 2-edge unroll with
// independent max chains. m init 0 = relu + zero-in-degree clamp.
// ---------------------------------------------------------------------------
__launch_bounds__(256)
__global__ void node_gather(const short* __restrict__ AB,
                            const int* __restrict__ row_ptr,
                            const int* __restrict__ edge_src,
                            short* __restrict__ c, int N)
{
    const int wave = threadIdx.x >> 6, lane = threadIdx.x & 63;
    const int d = blockIdx.x * 4 + wave;
    if (d >= N) return;

    const int beg = row_ptr[d], end = row_ptr[d + 1];
    const unsigned bdp = *(const unsigned*)&AB[(size_t)d * 256 + 128 + lane * 2];
    const float bd0 = __uint_as_float(bdp << 16);
    const float bd1 = __uint_as_float(bdp & 0xFFFF0000u);
    float m0a = 0.f, m1a = 0.f, m0b = 0.f, m1b = 0.f;

    for (int base = beg; base < end; base += 64) {
        const int cnt = min(64, end - base);
        const int sv = (lane < cnt) ? edge_src[base + lane] : 0;
        int i = 0;
        for (; i + 2 <= cnt; i += 2) {
            const int sA = __shfl(sv, i);
            const int sB = __shfl(sv, i + 1);
            const size_t qA = (size_t)sA * 256 + lane * 2;
            const size_t qB = (size_t)sB * 256 + lane * 2;
            const unsigned aA = *(const unsigned*)&AB[qA];
            const unsigned bA = *(const unsigned*)&AB[qA + 128];
            const unsigned aB = *(const unsigned*)&AB[qB];
            const unsigned bB = *(const unsigned*)&AB[qB + 128];

            const float eA0 = __uint_as_float(bA << 16) + bd0;
            const float eA1 = __uint_as_float(bA & 0xFFFF0000u) + bd1;
            const float pA0 = __fdividef(__uint_as_float(aA << 16), 1.f + __expf(-eA0));
            const float pA1 = __fdividef(__uint_as_float(aA & 0xFFFF0000u), 1.f + __expf(-eA1));
            m0a = fmaxf(m0a, pA0);
            m1a = fmaxf(m1a, pA1);

            const float eB0 = __uint_as_float(bB << 16) + bd0;
            const float eB1 = __uint_as_float(bB & 0xFFFF0000u) + bd1;
            const float pB0 = __fdividef(__uint_as_float(aB << 16), 1.f + __expf(-eB0));
            const float pB1 = __fdividef(__uint_as_float(aB & 0xFFFF0000u), 1.f + __expf(-eB1));
            m0b = fmaxf(m0b, pB0);
            m1b = fmaxf(m1b, pB1);
        }
        if (i < cnt) {
            const int s = __shfl(sv, i);
            const size_t q = (size_t)s * 256 + lane * 2;
            const unsigned aa = *(const unsigned*)&AB[q];
            const unsigned bb = *(const unsigned*)&AB[q + 128];
            const float e0 = __uint_as_float(bb << 16) + bd0;
            const float e1 = __uint_as_float(bb & 0xFFFF0000u) + bd1;
            const float p0 = __fdividef(__uint_as_float(aa << 16), 1.f + __expf(-e0));
            const float p1 = __fdividef(__uint_as_float(aa & 0xFFFF0000u), 1.f + __expf(-e1));
            m0a = fmaxf(m0a, p0);
            m1a = fmaxf(m1a, p1);
        }
    }
    const float m0 = fmaxf(m0a, m0b);
    const float m1 = fmaxf(m1a, m1b);
    const unsigned packed = (unsigned)f2bf(m0) | ((unsigned)f2bf(m1) << 16);
    *(unsigned*)&c[(size_t)d * D + lane * 2] = packed;
}

// ---------------------------------------------------------------------------
// Kernel 3: bundle = [h|c]@Wn + bn (bf16 MFMA, K=256); L2-norm; relu; residual.
// ---------------------------------------------------------------------------
__launch_bounds__(256)
__global__ void node_apply_mfma(const float* __restrict__ h,
                                const short* __restrict__ c,
                                const short* __restrict__ Wn_t,
                                const float* __restrict__ bn,
                                float* __restrict__ out, int N)
{
    const int tid = threadIdx.x, w = tid >> 6, l = tid & 63;
    const int rbase = blockIdx.x * 64 + w * 16;
    if (rbase >= N) return;
    const int g = l >> 4, r = l & 15;

    const float* hrow = h + (size_t)(rbase + r) * D + g * 8;
    const short* crow = c + (size_t)(rbase + r) * D + g * 8;

    f32x4 acc[8];
    #pragma unroll
    for (int t = 0; t < 8; ++t) acc[t] = (f32x4){0.f, 0.f, 0.f, 0.f};

    #pragma unroll
    for (int s = 0; s < 8; ++s) {
        s16x8 af;
        if (s < 4) {
            float4 lo = *(const float4*)(hrow + s * 32);
            float4 hi = *(const float4*)(hrow + s * 32 + 4);
            af = pack2(lo, hi);
        } else {
            af = *(const s16x8*)(crow + (s - 4) * 32);
        }
        #pragma unroll
        for (int t = 0; t < 8; ++t) {
            s16x8 bf = *(const s16x8*)(Wn_t + (size_t)(t * 16 + r) * 256 + s * 32 + g * 8);
            acc[t] = __builtin_amdgcn_mfma_f32_16x16x32_bf16(af, bf, acc[t], 0, 0, 0);
        }
    }

    float v[8][4];
    float ss[4] = {0.f, 0.f, 0.f, 0.f};
    #pragma unroll
    for (int t = 0; t < 8; ++t) {
        const float bb = bn[t * 16 + r];
        #pragma unroll
        for (int q = 0; q < 4; ++q) {
            const float x = acc[t][q] + bb;
            v[t][q] = x;
            ss[q] += x * x;
        }
    }
    #pragma unroll
    for (int m = 1; m < 16; m <<= 1) {      // reduce across the 16 lanes of a group
        #pragma unroll
        for (int q = 0; q < 4; ++q) ss[q] += __shfl_xor(ss[q], m);
    }
    float inv[4];
    #pragma unroll
    for (int q = 0; q < 4; ++q) inv[q] = 1.0f / fmaxf(sqrtf(ss[q]), 1e-12f);

    #pragma unroll
    for (int t = 0; t < 8; ++t) {
        const int col = t * 16 + r;
        #pragma unroll
        for (int q = 0; q < 4; ++q) {
            const size_t o = (size_t)(rbase + g * 4 + q) * D + col;
            out[o] = h[o] + fmaxf(v[t][q] * inv[q], 0.0f);
        }
    }
}

// ---------------------------------------------------------------------------
extern "C" void kernel_launch(void* const* d_in, const int* in_sizes, int n_in,
                              void* d_out, int out_size, void* d_ws, size_t ws_size,
                              hipStream_t stream)
{
    const float* h   = (const float*)d_in[0];
    const int*   src = (const int*)  d_in[1];
    const int*   dst = (const int*)  d_in[2];
    const float* WA  = (const float*)d_in[3];
    const float* bA  = (const float*)d_in[4];
    const float* WB  = (const float*)d_in[5];
    const float* bB  = (const float*)d_in[6];
    const float* Wn  = (const float*)d_in[7];
    const float* bn  = (const float*)d_in[8];

    const int N = in_sizes[0] / D;
    const int E = in_sizes[1];

    // workspace layout (~42 MB; rounds 6-7 prove ws >= ~55 MB)
    const size_t npad = (size_t)((N + 4 + 3) / 4) * 4;
    const size_t n4   = (size_t)((N + 3) / 4) * 4;
    short* AB         = (short*)d_ws;                 // [N][256] bf16
    short* c_bf       = AB + (size_t)N * 256;         // [N][128] bf16
    short* Wab_t      = c_bf + (size_t)N * D;         // [256][128] bf16
    short* Wn_t       = Wab_t + 256 * 128;            // [128][256] bf16
    float* bias_ab    = (float*)(Wn_t + 128 * 256);   // [256]
    int*   row_ptr    = (int*)(bias_ab + 256);
    int*   cursor     = row_ptr + npad;
    int*   cnt_buf    = cursor + n4;
    int*   block_sums = cnt_buf + n4;
    int*   block_offs = block_sums + 1024;
    int*   edge_src   = block_offs + 1024;

    hipMemsetAsync(cnt_buf, 0, (size_t)N * sizeof(int), stream);

    prep_weights<<<384, 256, 0, stream>>>(WA, bA, WB, bB, Wn, Wab_t, Wn_t, bias_ab);

    const int gb = (N + 63) / 64;
    gemm_ab_mfma<<<gb, 256, 0, stream>>>(h, Wab_t, bias_ab, AB, N);

    const int eb = (E + 255) / 256;
    const int NB = (N + SCAN_EPB - 1) / SCAN_EPB;
    hist_kernel<<<eb, 256, 0, stream>>>(dst, cnt_buf, E);
    scan_pass1<<<NB, 256, 0, stream>>>(cnt_buf, block_sums, N);
    scan_pass2<<<1, 1024, 0, stream>>>(block_sums, block_offs, NB);
    scan_pass3<<<NB, 256, 0, stream>>>(cnt_buf, block_offs, row_ptr, cursor, N, E);
    scatter_kernel<<<eb, 256, 0, stream>>>(src, dst, cursor, edge_src, E);

    node_gather<<<(N + 3) / 4, 256, 0, stream>>>(AB, row_ptr, edge_src, c_bf, N);

    node_apply_mfma<<<gb, 256, 0, stream>>>(h, c_bf, Wn_t, bn, (float*)d_out, N);
}